// Round 1
// baseline (2292.134 us; speedup 1.0000x reference)
//
#include <hip/hip_runtime.h>
#include <cstdint>
#include <cstddef>

#define B_DIM 128
#define T_LEN 2048
#define C_DIM 128
#define NSTEP (T_LEN - 1)

// Forward Viterbi: one block per batch, 256 threads.
// Thread (h = tid>>6, j2 = tid&63) covers i in [32h, 32h+32) for outputs
// j in {j2, j2+64}. trans column slices live in registers (64 VGPRs).
__global__ __launch_bounds__(256) void viterbi_fwd(
    const float* __restrict__ pot,
    const float* __restrict__ trans,
    unsigned char* __restrict__ bp,
    int* __restrict__ lastTag)
{
    const int b   = blockIdx.x;
    const int tid = threadIdx.x;
    const int j2  = tid & 63;
    const int h   = tid >> 6;

    __shared__ __align__(16) float alpha[C_DIM];
    __shared__ float pv[4][C_DIM];
    __shared__ int   pi[4][C_DIM];

    // trans[i][j] for i = 32h..32h+31, j = j2 and j2+64 -> registers
    float tr0[32], tr1[32];
#pragma unroll
    for (int k = 0; k < 32; ++k) {
        tr0[k] = trans[(32 * h + k) * C_DIM + j2];
        tr1[k] = trans[(32 * h + k) * C_DIM + j2 + 64];
    }

    const float* potb = pot + (size_t)b * T_LEN * C_DIM;
    if (tid < C_DIM) alpha[tid] = potb[tid];   // alpha0 = potentials[:,0]
    __syncthreads();

    const int jc = tid & 127;                  // combine-phase j
    float pc = potb[1 * C_DIM + jc];           // pot for t=1 (prefetched)

    for (int t = 1; t < T_LEN; ++t) {
        // prefetch pot for t+1 (independent of this step's compute)
        float pn = 0.0f;
        if (t + 1 < T_LEN) pn = potb[(t + 1) * C_DIM + jc];

        float best0 = -INFINITY, best1 = -INFINITY;
        int bi0 = 0, bi1 = 0;
        const float4* a4 = (const float4*)(&alpha[32 * h]);
#pragma unroll
        for (int q = 0; q < 8; ++q) {
            float4 av = a4[q];                 // broadcast LDS read (wave-uniform addr)
            float aa[4] = {av.x, av.y, av.z, av.w};
#pragma unroll
            for (int e = 0; e < 4; ++e) {
                const int k = 4 * q + e;
                float s0 = aa[e] + tr0[k];
                bi0 = (s0 <= best0) ? bi0 : k;  // strict > keeps first (lowest i)
                best0 = fmaxf(best0, s0);
                float s1 = aa[e] + tr1[k];
                bi1 = (s1 <= best1) ? bi1 : k;
                best1 = fmaxf(best1, s1);
            }
        }
        pv[h][j2]      = best0;
        pi[h][j2]      = 32 * h + bi0;
        pv[h][j2 + 64] = best1;
        pi[h][j2 + 64] = 32 * h + bi1;
        __syncthreads();

        if (tid < C_DIM) {
            float v = pv[0][jc];
            int  ix = pi[0][jc];
#pragma unroll
            for (int hh = 1; hh < 4; ++hh) {
                float w = pv[hh][jc];
                ix = (w <= v) ? ix : pi[hh][jc];  // strict > => lowest h wins ties
                v  = fmaxf(v, w);
            }
            alpha[jc] = v + pc;
            bp[(size_t)(t - 1) * (B_DIM * C_DIM) + (size_t)b * C_DIM + jc] =
                (unsigned char)ix;
        }
        __syncthreads();
        pc = pn;
    }

    // last_tag = first-index argmax of alpha_T
    if (tid == 0) {
        float v = alpha[0];
        int  ix = 0;
        for (int j = 1; j < C_DIM; ++j) {
            float w = alpha[j];
            if (w > v) { v = w; ix = j; }
        }
        lastTag[b] = ix;
    }
}

// Backtrack: one block (1 wave) per batch. Row of 128 backpointer bytes is
// held packed 4/lane in lanes 0..31; cur = row[cur] resolved in-register via
// ds_bpermute + byte extract. Rows prefetched 8 deep (addresses independent).
__global__ __launch_bounds__(64) void viterbi_bwd(
    const unsigned char* __restrict__ bp,
    const int* __restrict__ lastTag,
    float* __restrict__ out)
{
    const int b    = blockIdx.x;
    const int lane = threadIdx.x;
    float* outb = out + (size_t)b * T_LEN;

    int cur = lastTag[b];
    if (lane == 0) outb[T_LEN - 1] = (float)cur;

    auto loadrow = [&](int s) -> unsigned {
        unsigned r = 0;
        if (s >= 0 && lane < 32)
            r = *(const unsigned*)(bp + ((size_t)s * B_DIM + b) * C_DIM + 4 * lane);
        return r;
    };

    unsigned rbuf[8];
#pragma unroll
    for (int p = 0; p < 8; ++p) rbuf[p] = loadrow(NSTEP - 1 - p);

    int s = NSTEP - 1;
    while (s >= 0) {
#pragma unroll
        for (int p = 0; p < 8; ++p) {
            if (s >= 0) {
                unsigned rowreg = rbuf[p];
                rbuf[p] = loadrow(s - 8);  // refill slot for 8 iters ahead
                int v = __builtin_amdgcn_ds_bpermute(cur & 0x7C, (int)rowreg);
                cur = (v >> ((cur & 3) * 8)) & 0xFF;
                if (lane == 0) outb[s] = (float)cur;
                --s;
            }
        }
    }
}

extern "C" void kernel_launch(void* const* d_in, const int* in_sizes, int n_in,
                              void* d_out, int out_size, void* d_ws, size_t ws_size,
                              hipStream_t stream)
{
    const float* pot   = (const float*)d_in[0];   // [128, 2048, 128] f32
    const float* trans = (const float*)d_in[1];   // [128, 128] f32
    float* out = (float*)d_out;                   // [128, 2048] f32 (tags)

    // ws: bp uint8[2047][128][128] (33,538,048 B) then lastTag int[128]
    unsigned char* bp = (unsigned char*)d_ws;
    int* lastTag = (int*)(bp + (size_t)NSTEP * B_DIM * C_DIM);

    viterbi_fwd<<<B_DIM, 256, 0, stream>>>(pot, trans, bp, lastTag);
    viterbi_bwd<<<B_DIM, 64, 0, stream>>>(bp, lastTag, out);
}